// Round 6
// baseline (16662.700 us; speedup 1.0000x reference)
//
#include <hip/hip_runtime.h>
#include <hip/hip_bf16.h>
#include <math.h>

// Problem constants (from reference)
#define BB   2
#define SS   2048
#define DD   1024
#define HH   16
#define FF   4096
#define LL   8
#define QN   128
#define DHD  64
#define MTOK (BB*SS)   // 4096 tokens
#define MCHUNK 1024    // MLP row-chunk (4 chunks) to cap workspace size

typedef __attribute__((ext_vector_type(8))) short s16x8;   // 8 bf16 (4 VGPRs) MFMA frag
typedef __attribute__((ext_vector_type(4))) unsigned short u16x4;
typedef __attribute__((ext_vector_type(4))) float f32x4;

static __device__ __forceinline__ float gelu_tanh(float x) {
  float x3 = x*x*x;
  return 0.5f*x*(1.0f + tanhf(0.7978845608028654f*(x + 0.044715f*x3)));
}

// f32 -> bf16 RNE, and hi/lo split (x ~= hi + lo, error ~2^-17 * |x|)
static __device__ __forceinline__ unsigned short f2bf(float x) {
  unsigned u = __float_as_uint(x);
  return (unsigned short)((u + 0x7FFFu + ((u >> 16) & 1u)) >> 16);
}
static __device__ __forceinline__ float bf2f(unsigned short h) {
  return __uint_as_float(((unsigned)h) << 16);
}
struct BfPair { unsigned short hi, lo; };
static __device__ __forceinline__ BfPair split2(float x) {
  BfPair p;
  p.hi = f2bf(x);
  p.lo = f2bf(x - bf2f(p.hi));
  return p;
}
// vector-element-safe assignment (clang can't bind non-const refs to vector elems)
#define SPLIT2(x, H, L) do { BfPair _p = split2(x); (H) = _p.hi; (L) = _p.lo; } while (0)

// ---------------- LayerNorm (f32 out): one block per row, D=1024 -------------------
__global__ __launch_bounds__(256) void ln_kernel(
    const float* __restrict__ x, int ldx,
    const float* __restrict__ g,
    float* __restrict__ y, int ldy) {
  const int row = blockIdx.x;
  const int t = threadIdx.x;
  const float4 v = reinterpret_cast<const float4*>(x + (size_t)row*ldx)[t];
  float s  = v.x+v.y+v.z+v.w;
  float s2 = v.x*v.x+v.y*v.y+v.z*v.z+v.w*v.w;
  #pragma unroll
  for (int o = 32; o > 0; o >>= 1) { s += __shfl_down(s, o); s2 += __shfl_down(s2, o); }
  __shared__ float red[8];
  const int wid = t >> 6;
  if ((t & 63) == 0) { red[wid] = s; red[wid+4] = s2; }
  __syncthreads();
  if (t == 0) {
    float ts = red[0]+red[1]+red[2]+red[3], ts2 = red[4]+red[5]+red[6]+red[7];
    float mean = ts * (1.0f/1024.0f);
    float var  = ts2 * (1.0f/1024.0f) - mean*mean;
    red[0] = mean; red[1] = rsqrtf(var + 1e-5f);
  }
  __syncthreads();
  const float mean = red[0], rstd = red[1];
  const float4 gv = reinterpret_cast<const float4*>(g)[t];
  float4 o;
  o.x = (v.x-mean)*rstd*gv.x; o.y = (v.y-mean)*rstd*gv.y;
  o.z = (v.z-mean)*rstd*gv.z; o.w = (v.w-mean)*rstd*gv.w;
  reinterpret_cast<float4*>(y + (size_t)row*ldy)[t] = o;
}

// ---------------- LayerNorm with bf16 hi/lo output ---------------------------------
__global__ __launch_bounds__(256) void ln_hilo_kernel(
    const float* __restrict__ x, int ldx,
    const float* __restrict__ g,
    unsigned short* __restrict__ Hi, unsigned short* __restrict__ Lo, int ldh) {
  const int row = blockIdx.x;
  const int t = threadIdx.x;
  const float4 v = reinterpret_cast<const float4*>(x + (size_t)row*ldx)[t];
  float s  = v.x+v.y+v.z+v.w;
  float s2 = v.x*v.x+v.y*v.y+v.z*v.z+v.w*v.w;
  #pragma unroll
  for (int o = 32; o > 0; o >>= 1) { s += __shfl_down(s, o); s2 += __shfl_down(s2, o); }
  __shared__ float red[8];
  const int wid = t >> 6;
  if ((t & 63) == 0) { red[wid] = s; red[wid+4] = s2; }
  __syncthreads();
  if (t == 0) {
    float ts = red[0]+red[1]+red[2]+red[3], ts2 = red[4]+red[5]+red[6]+red[7];
    float mean = ts * (1.0f/1024.0f);
    float var  = ts2 * (1.0f/1024.0f) - mean*mean;
    red[0] = mean; red[1] = rsqrtf(var + 1e-5f);
  }
  __syncthreads();
  const float mean = red[0], rstd = red[1];
  const float4 gv = reinterpret_cast<const float4*>(g)[t];
  float o0 = (v.x-mean)*rstd*gv.x, o1 = (v.y-mean)*rstd*gv.y;
  float o2 = (v.z-mean)*rstd*gv.z, o3 = (v.w-mean)*rstd*gv.w;
  u16x4 hh, ll;
  SPLIT2(o0, hh[0], ll[0]); SPLIT2(o1, hh[1], ll[1]);
  SPLIT2(o2, hh[2], ll[2]); SPLIT2(o3, hh[3], ll[3]);
  *(u16x4*)(Hi + (size_t)row*ldh + t*4) = hh;
  *(u16x4*)(Lo + (size_t)row*ldh + t*4) = ll;
}

// ---------------- f32 -> bf16 hi/lo convert (flat, grid-stride over float4) --------
__global__ __launch_bounds__(256) void conv_hilo(
    const float* __restrict__ X,
    unsigned short* __restrict__ Hi, unsigned short* __restrict__ Lo, int n4) {
  for (int i = blockIdx.x*256 + threadIdx.x; i < n4; i += gridDim.x*256) {
    const float4 x = reinterpret_cast<const float4*>(X)[i];
    u16x4 h, l;
    SPLIT2(x.x, h[0], l[0]); SPLIT2(x.y, h[1], l[1]);
    SPLIT2(x.z, h[2], l[2]); SPLIT2(x.w, h[3], l[3]);
    reinterpret_cast<u16x4*>(Hi)[i] = h;
    reinterpret_cast<u16x4*>(Lo)[i] = l;
  }
}

// ---------------- transpose+split: W[K][N] f32 -> T[N][K] bf16 hi/lo ---------------
__global__ __launch_bounds__(256) void transpose_hilo(
    const float* __restrict__ W, int K, int N,
    unsigned short* __restrict__ Thi, unsigned short* __restrict__ Tlo) {
  __shared__ unsigned short th[32][33];
  __shared__ unsigned short tl[32][33];
  const int kb = blockIdx.y << 5, nb = blockIdx.x << 5;
  const int t = threadIdx.x;
  const int r = t >> 3, c = (t & 7) << 2;     // r: 0..31, c: 0..28 step 4
  const float4 wv = *(const float4*)(W + (size_t)(kb + r)*N + nb + c);
  SPLIT2(wv.x, th[r][c+0], tl[r][c+0]);
  SPLIT2(wv.y, th[r][c+1], tl[r][c+1]);
  SPLIT2(wv.z, th[r][c+2], tl[r][c+2]);
  SPLIT2(wv.w, th[r][c+3], tl[r][c+3]);
  __syncthreads();
  u16x4 oh, ol;
  #pragma unroll
  for (int j = 0; j < 4; ++j) { oh[j] = th[c+j][r]; ol[j] = tl[c+j][r]; }
  *(u16x4*)(Thi + (size_t)(nb + r)*K + kb + c) = oh;
  *(u16x4*)(Tlo + (size_t)(nb + r)*K + kb + c) = ol;
}

// ---------------- MFMA GEMM (bf16 hi/lo split, fp32-grade accuracy) ----------------
// C[M,N] = A[M,K] @ W[K,N]; A given as Ahi/Alo bf16 [M][lda]; W as Whi/Wlo [N][K]
// (k-contiguous both). tile 128x128, BK=32, 4 waves (2x2), each wave 64x64 = 4x4
// frags of 16x16. 3 MFMAs per frag pair: hi*hi + hi*lo + lo*hi.
// mode: 0 = f32 C; 1 = f32 C + relu; 2 = bf16 hi/lo C + relu.
#define RS 56   // LDS row stride in halves: 112B = 16B-aligned, 28-bank stride (~2-way max)
__global__ __launch_bounds__(256) void gemm_mfma(
    const unsigned short* __restrict__ Ahi, const unsigned short* __restrict__ Alo, int lda,
    const unsigned short* __restrict__ Whi, const unsigned short* __restrict__ Wlo,
    int N, int K,
    const float* __restrict__ bias,
    const float* __restrict__ res, int ldres,
    float* __restrict__ C, int ldc,
    unsigned short* __restrict__ Chi, unsigned short* __restrict__ Clo,
    int mode) {
  __shared__ __align__(16) unsigned short sAh[128*RS];
  __shared__ __align__(16) unsigned short sAl[128*RS];
  __shared__ __align__(16) unsigned short sBh[128*RS];
  __shared__ __align__(16) unsigned short sBl[128*RS];
  const int t = threadIdx.x;
  const int lane = t & 63;
  const int w = t >> 6;
  const int wr = w >> 1, wc = w & 1;          // wave grid 2x2 over the 128x128 tile
  const int m0 = blockIdx.y * 128, n0 = blockIdx.x * 128;
  const int fr = lane & 15;                   // frag row (A) / col (B)
  const int ko = lane >> 4;                   // k-octet 0..3

  f32x4 acc[4][4];
  #pragma unroll
  for (int i = 0; i < 4; ++i)
    #pragma unroll
    for (int j = 0; j < 4; ++j) acc[i][j] = f32x4{0.f, 0.f, 0.f, 0.f};

  for (int k0 = 0; k0 < K; k0 += 32) {
    #pragma unroll
    for (int u = 0; u < 2; ++u) {
      const int id = t + u*256;
      const int row = id >> 2, cc = (id & 3) << 3;   // 4 octets per 32-wide row
      *(s16x8*)&sAh[row*RS + cc] = *(const s16x8*)(Ahi + (size_t)(m0+row)*lda + k0 + cc);
      *(s16x8*)&sAl[row*RS + cc] = *(const s16x8*)(Alo + (size_t)(m0+row)*lda + k0 + cc);
      *(s16x8*)&sBh[row*RS + cc] = *(const s16x8*)(Whi + (size_t)(n0+row)*K  + k0 + cc);
      *(s16x8*)&sBl[row*RS + cc] = *(const s16x8*)(Wlo + (size_t)(n0+row)*K  + k0 + cc);
    }
    __syncthreads();
    s16x8 ah[4], al[4], bh[4], bl[4];
    #pragma unroll
    for (int mi = 0; mi < 4; ++mi) {
      const int r = (wr*64 + mi*16 + fr)*RS + ko*8;
      ah[mi] = *(const s16x8*)&sAh[r];
      al[mi] = *(const s16x8*)&sAl[r];
    }
    #pragma unroll
    for (int nj = 0; nj < 4; ++nj) {
      const int r = (wc*64 + nj*16 + fr)*RS + ko*8;
      bh[nj] = *(const s16x8*)&sBh[r];
      bl[nj] = *(const s16x8*)&sBl[r];
    }
    #pragma unroll
    for (int mi = 0; mi < 4; ++mi)
      #pragma unroll
      for (int nj = 0; nj < 4; ++nj) {
        acc[mi][nj] = __builtin_amdgcn_mfma_f32_16x16x32_bf16(ah[mi], bh[nj], acc[mi][nj], 0, 0, 0);
        acc[mi][nj] = __builtin_amdgcn_mfma_f32_16x16x32_bf16(ah[mi], bl[nj], acc[mi][nj], 0, 0, 0);
        acc[mi][nj] = __builtin_amdgcn_mfma_f32_16x16x32_bf16(al[mi], bh[nj], acc[mi][nj], 0, 0, 0);
      }
    __syncthreads();
  }
  // epilogue: C/D layout col = lane&15, row = (lane>>4)*4 + reg (m89/m91-verified)
  #pragma unroll
  for (int mi = 0; mi < 4; ++mi) {
    #pragma unroll
    for (int nj = 0; nj < 4; ++nj) {
      const int gn = n0 + wc*64 + nj*16 + fr;
      const float bv = bias ? bias[gn] : 0.f;
      #pragma unroll
      for (int r2 = 0; r2 < 4; ++r2) {
        const int gm = m0 + wr*64 + mi*16 + ko*4 + r2;
        float v = acc[mi][nj][r2] + bv;
        if (res)  v += res[(size_t)gm*ldres + gn];
        if (mode >= 1) v = fmaxf(v, 0.f);
        if (mode == 2) {
          BfPair pr = split2(v);
          Chi[(size_t)gm*ldc + gn] = pr.hi;
          Clo[(size_t)gm*ldc + gn] = pr.lo;
        } else {
          C[(size_t)gm*ldc + gn] = v;
        }
      }
    }
  }
}

// ---------------- fp32 SIMT GEMM (fallback + tiny head-final GEMMs) ----------------
__global__ __launch_bounds__(256) void gemm_f32(
    const float* __restrict__ A, int lda,
    const float* __restrict__ W, int ldw, int N, int K,
    const float* __restrict__ bias,
    const float* __restrict__ res, int ldres,
    float* __restrict__ C, int ldc, int relu) {
  __shared__ float As[16][132];
  __shared__ float Bs[16][132];
  const int t  = threadIdx.x;
  const int tx = t & 15, ty = t >> 4;
  const int m0 = blockIdx.y * 128, n0 = blockIdx.x * 128;
  float acc[8][8];
  #pragma unroll
  for (int i = 0; i < 8; ++i)
    #pragma unroll
    for (int j = 0; j < 8; ++j) acc[i][j] = 0.f;
  const bool nvec = ((N & 3) == 0) && (n0 + 128 <= N);

  for (int k0 = 0; k0 < K; k0 += 16) {
    #pragma unroll
    for (int u = 0; u < 2; ++u) {
      const int id  = t + u*256;
      const int row = id >> 2, c4 = (id & 3) << 2;
      const float4 a = *reinterpret_cast<const float4*>(A + (size_t)(m0+row)*lda + k0 + c4);
      As[c4+0][row] = a.x; As[c4+1][row] = a.y; As[c4+2][row] = a.z; As[c4+3][row] = a.w;
    }
    if (nvec) {
      #pragma unroll
      for (int u = 0; u < 2; ++u) {
        const int id = t + u*256;
        const int kr = id >> 5, nc = (id & 31) << 2;
        *reinterpret_cast<float4*>(&Bs[kr][nc]) =
            *reinterpret_cast<const float4*>(W + (size_t)(k0+kr)*ldw + n0 + nc);
      }
    } else {
      #pragma unroll
      for (int u = 0; u < 2; ++u) {
        const int id = t + u*256;
        const int kr = id >> 5, nc = (id & 31) << 2;
        #pragma unroll
        for (int j = 0; j < 4; ++j) {
          const int gn = n0 + nc + j;
          Bs[kr][nc+j] = (gn < N) ? W[(size_t)(k0+kr)*ldw + gn] : 0.f;
        }
      }
    }
    __syncthreads();
    #pragma unroll
    for (int k = 0; k < 16; ++k) {
      float ra[8], rb[8];
      *reinterpret_cast<float4*>(ra)   = *reinterpret_cast<const float4*>(&As[k][ty*8]);
      *reinterpret_cast<float4*>(ra+4) = *reinterpret_cast<const float4*>(&As[k][ty*8+4]);
      *reinterpret_cast<float4*>(rb)   = *reinterpret_cast<const float4*>(&Bs[k][tx*8]);
      *reinterpret_cast<float4*>(rb+4) = *reinterpret_cast<const float4*>(&Bs[k][tx*8+4]);
      #pragma unroll
      for (int i = 0; i < 8; ++i)
        #pragma unroll
        for (int j = 0; j < 8; ++j)
          acc[i][j] = fmaf(ra[i], rb[j], acc[i][j]);
    }
    __syncthreads();
  }
  #pragma unroll
  for (int i = 0; i < 8; ++i) {
    const int gm = m0 + ty*8 + i;
    float* crow = C + (size_t)gm*ldc;
    const float* rrow = res ? (res + (size_t)gm*ldres) : nullptr;
    #pragma unroll
    for (int j = 0; j < 8; ++j) {
      const int gn = n0 + tx*8 + j;
      if (gn < N) {
        float v = acc[i][j];
        if (bias) v += bias[gn];
        if (rrow) v += rrow[gn];
        if (relu) v = fmaxf(v, 0.f);
        crow[gn] = v;
      }
    }
  }
}

// ---------------- Flash attention fp32, causal. qkv [MTOK, 3*DD] -------------------
__global__ __launch_bounds__(256) void attn_kernel(
    const float* __restrict__ qkv, float* __restrict__ out) {
  const int qt = (int)gridDim.x - 1 - (int)blockIdx.x;
  const int h = blockIdx.y, b = blockIdx.z;
  const int t = threadIdx.x;
  const int ti = t >> 4, tj = t & 15;
  __shared__ float Qs[64][65];
  __shared__ float KVs[64][65];
  __shared__ float Ps[64][65];
  const size_t base = (size_t)b * SS * (3*DD);

  const int r_  = t >> 2;
  const int c0_ = (t & 3) * 16;
  {
    const float* src = qkv + base + (size_t)(qt*64 + r_)*(3*DD) + h*DHD + c0_;
    float4 vv[4];
    #pragma unroll
    for (int u = 0; u < 4; ++u) vv[u] = reinterpret_cast<const float4*>(src)[u];
    #pragma unroll
    for (int u = 0; u < 4; ++u) {
      Qs[r_][c0_+u*4+0] = vv[u].x; Qs[r_][c0_+u*4+1] = vv[u].y;
      Qs[r_][c0_+u*4+2] = vv[u].z; Qs[r_][c0_+u*4+3] = vv[u].w;
    }
  }

  float oacc[4][4];
  float m_r[4], l_r[4];
  #pragma unroll
  for (int i = 0; i < 4; ++i) {
    m_r[i] = -1e30f; l_r[i] = 0.f;
    #pragma unroll
    for (int d = 0; d < 4; ++d) oacc[i][d] = 0.f;
  }

  for (int kt = 0; kt <= qt; ++kt) {
    const float* ksrc = qkv + base + (size_t)(kt*64 + r_)*(3*DD) + DD   + h*DHD + c0_;
    const float* vsrc = qkv + base + (size_t)(kt*64 + r_)*(3*DD) + 2*DD + h*DHD + c0_;
    float4 kv[4], vv[4];
    #pragma unroll
    for (int u = 0; u < 4; ++u) kv[u] = reinterpret_cast<const float4*>(ksrc)[u];
    #pragma unroll
    for (int u = 0; u < 4; ++u) vv[u] = reinterpret_cast<const float4*>(vsrc)[u];

    __syncthreads();
    #pragma unroll
    for (int u = 0; u < 4; ++u) {
      KVs[r_][c0_+u*4+0] = kv[u].x; KVs[r_][c0_+u*4+1] = kv[u].y;
      KVs[r_][c0_+u*4+2] = kv[u].z; KVs[r_][c0_+u*4+3] = kv[u].w;
    }
    __syncthreads();

    float s[4][4];
    #pragma unroll
    for (int i = 0; i < 4; ++i)
      #pragma unroll
      for (int j = 0; j < 4; ++j) s[i][j] = 0.f;
    for (int d = 0; d < 64; ++d) {
      float qv[4], kk[4];
      #pragma unroll
      for (int i = 0; i < 4; ++i) qv[i] = Qs[ti*4+i][d];
      #pragma unroll
      for (int j = 0; j < 4; ++j) kk[j] = KVs[tj*4+j][d];
      #pragma unroll
      for (int i = 0; i < 4; ++i)
        #pragma unroll
        for (int j = 0; j < 4; ++j)
          s[i][j] = fmaf(qv[i], kk[j], s[i][j]);
    }
    if (kt == qt) {
      #pragma unroll
      for (int i = 0; i < 4; ++i) {
        const int qi = qt*64 + ti*4 + i;
        #pragma unroll
        for (int j = 0; j < 4; ++j) {
          const int kj = kt*64 + tj*4 + j;
          s[i][j] = (kj > qi) ? -1e30f : s[i][j]*0.125f;
        }
      }
    } else {
      #pragma unroll
      for (int i = 0; i < 4; ++i)
        #pragma unroll
        for (int j = 0; j < 4; ++j) s[i][j] *= 0.125f;
    }
    float p[4][4];
    #pragma unroll
    for (int i = 0; i < 4; ++i) {
      float tm = fmaxf(fmaxf(s[i][0], s[i][1]), fmaxf(s[i][2], s[i][3]));
      #pragma unroll
      for (int o = 1; o < 16; o <<= 1) tm = fmaxf(tm, __shfl_xor(tm, o));
      const float mn = fmaxf(m_r[i], tm);
      const float corr = expf(m_r[i] - mn);
      float sum = 0.f;
      #pragma unroll
      for (int j = 0; j < 4; ++j) { p[i][j] = expf(s[i][j] - mn); sum += p[i][j]; }
      #pragma unroll
      for (int o = 1; o < 16; o <<= 1) sum += __shfl_xor(sum, o);
      l_r[i] = l_r[i]*corr + sum;
      m_r[i] = mn;
      #pragma unroll
      for (int d = 0; d < 4; ++d) oacc[i][d] *= corr;
    }
    __syncthreads();
    #pragma unroll
    for (int u = 0; u < 4; ++u) {
      KVs[r_][c0_+u*4+0] = vv[u].x; KVs[r_][c0_+u*4+1] = vv[u].y;
      KVs[r_][c0_+u*4+2] = vv[u].z; KVs[r_][c0_+u*4+3] = vv[u].w;
    }
    #pragma unroll
    for (int i = 0; i < 4; ++i)
      #pragma unroll
      for (int j = 0; j < 4; ++j) Ps[ti*4+i][tj*4+j] = p[i][j];
    __syncthreads();

    for (int j = 0; j < 64; ++j) {
      float pr[4], vr[4];
      #pragma unroll
      for (int i = 0; i < 4; ++i) pr[i] = Ps[ti*4+i][j];
      #pragma unroll
      for (int d = 0; d < 4; ++d) vr[d] = KVs[j][tj*4+d];
      #pragma unroll
      for (int i = 0; i < 4; ++i)
        #pragma unroll
        for (int d = 0; d < 4; ++d)
          oacc[i][d] = fmaf(pr[i], vr[d], oacc[i][d]);
    }
  }

  #pragma unroll
  for (int i = 0; i < 4; ++i) {
    const float inv = 1.0f / l_r[i];
    const int gq = qt*64 + ti*4 + i;
    float4 o4;
    o4.x = oacc[i][0]*inv; o4.y = oacc[i][1]*inv;
    o4.z = oacc[i][2]*inv; o4.w = oacc[i][3]*inv;
    *reinterpret_cast<float4*>(out + ((size_t)(b*SS + gq))*DD + h*DHD + tj*4) = o4;
  }
}

// ---------------- GEGLU f32 out (fallback) -----------------------------------------
__global__ __launch_bounds__(256) void geglu_kernel(
    const float* __restrict__ uv, float* __restrict__ out) {
  const int idx = blockIdx.x * 256 + threadIdx.x;
  const int row = idx >> 10;
  const int c4  = (idx & 1023) << 2;
  const float* prow = uv + (size_t)row * (2*FF);
  const float4 u = *reinterpret_cast<const float4*>(prow + c4);
  const float4 g = *reinterpret_cast<const float4*>(prow + FF + c4);
  float4 o;
  o.x = u.x * gelu_tanh(g.x); o.y = u.y * gelu_tanh(g.y);
  o.z = u.z * gelu_tanh(g.z); o.w = u.w * gelu_tanh(g.w);
  *reinterpret_cast<float4*>(out + (size_t)row * FF + c4) = o;
}

// ---------------- GEGLU with bf16 hi/lo output -------------------------------------
__global__ __launch_bounds__(256) void geglu_hilo(
    const float* __restrict__ uv,
    unsigned short* __restrict__ Hi, unsigned short* __restrict__ Lo) {
  const int idx = blockIdx.x * 256 + threadIdx.x;
  const int row = idx >> 10;
  const int c4  = (idx & 1023) << 2;
  const float* prow = uv + (size_t)row * (2*FF);
  const float4 u = *reinterpret_cast<const float4*>(prow + c4);
  const float4 g = *reinterpret_cast<const float4*>(prow + FF + c4);
  u16x4 hh, ll;
  SPLIT2(u.x * gelu_tanh(g.x), hh[0], ll[0]);
  SPLIT2(u.y * gelu_tanh(g.y), hh[1], ll[1]);
  SPLIT2(u.z * gelu_tanh(g.z), hh[2], ll[2]);
  SPLIT2(u.w * gelu_tanh(g.w), hh[3], ll[3]);
  *(u16x4*)(Hi + (size_t)row*FF + c4) = hh;
  *(u16x4*)(Lo + (size_t)row*FF + c4) = ll;
}

// ---------------- embedding gathers ------------------------------------------------
__global__ __launch_bounds__(256) void gather_kernel(
    const int* __restrict__ c1, const int* __restrict__ c2,
    const float* __restrict__ emb1, const float* __restrict__ emb2,
    float* __restrict__ cat) {
  const int row = blockIdx.x, t = threadIdx.x;
  const int i1 = c1[row], i2 = c2[row];
  const float4 v1 = reinterpret_cast<const float4*>(emb1 + (size_t)i1*DD)[t];
  const float4 v2 = reinterpret_cast<const float4*>(emb2 + (size_t)i2*DD)[t];
  reinterpret_cast<float4*>(cat + (size_t)row*(3*DD) + DD)[t]   = v1;
  reinterpret_cast<float4*>(cat + (size_t)row*(3*DD) + 2*DD)[t] = v2;
}

__global__ __launch_bounds__(256) void gather_hilo(
    const int* __restrict__ c1, const int* __restrict__ c2,
    const float* __restrict__ emb1, const float* __restrict__ emb2,
    unsigned short* __restrict__ Hi, unsigned short* __restrict__ Lo) {
  const int row = blockIdx.x, t = threadIdx.x;
  const int i1 = c1[row], i2 = c2[row];
  const float4 v1 = reinterpret_cast<const float4*>(emb1 + (size_t)i1*DD)[t];
  const float4 v2 = reinterpret_cast<const float4*>(emb2 + (size_t)i2*DD)[t];
  u16x4 h1, l1, h2, l2;
  SPLIT2(v1.x, h1[0], l1[0]); SPLIT2(v1.y, h1[1], l1[1]);
  SPLIT2(v1.z, h1[2], l1[2]); SPLIT2(v1.w, h1[3], l1[3]);
  SPLIT2(v2.x, h2[0], l2[0]); SPLIT2(v2.y, h2[1], l2[1]);
  SPLIT2(v2.z, h2[2], l2[2]); SPLIT2(v2.w, h2[3], l2[3]);
  const size_t rb = (size_t)row*(3*DD);
  *(u16x4*)(Hi + rb + DD   + t*4) = h1;  *(u16x4*)(Lo + rb + DD   + t*4) = l1;
  *(u16x4*)(Hi + rb + 2*DD + t*4) = h2;  *(u16x4*)(Lo + rb + 2*DD + t*4) = l2;
}

// ===================================================================================
extern "C" void kernel_launch(void* const* d_in, const int* in_sizes, int n_in,
                              void* d_out, int out_size, void* d_ws, size_t ws_size,
                              hipStream_t stream) {
  (void)in_sizes; (void)n_in;
  const float* acc_fea = (const float*)d_in[0];
  const int*   c1      = (const int*)d_in[1];
  const int*   c2      = (const int*)d_in[2];
  const float* ln1  = (const float*)d_in[3];
  const float* wqkv = (const float*)d_in[4];
  const float* bqkv = (const float*)d_in[5];
  const float* wo   = (const float*)d_in[6];
  const float* bo   = (const float*)d_in[7];
  const float* ln2  = (const float*)d_in[8];
  const float* w1   = (const float*)d_in[9];
  const float* b1   = (const float*)d_in[10];
  const float* w2   = (const float*)d_in[11];
  const float* b2   = (const float*)d_in[12];
  const float* lnf  = (const float*)d_in[13];
  const float* emb1 = (const float*)d_in[14];
  const float* emb2 = (const float*)d_in[15];
  const float* h1w1 = (const float*)d_in[16]; const float* h1b1 = (const float*)d_in[17];
  const float* h1w2 = (const float*)d_in[18]; const float* h1b2 = (const float*)d_in[19];
  const float* h1w3 = (const float*)d_in[20]; const float* h1b3 = (const float*)d_in[21];
  const float* h2w1 = (const float*)d_in[22]; const float* h2b1 = (const float*)d_in[23];
  const float* h2w2 = (const float*)d_in[24]; const float* h2b2 = (const float*)d_in[25];
  const float* h2w3 = (const float*)d_in[26]; const float* h2b3 = (const float*)d_in[27];
  const float* h3w1 = (const float*)d_in[28]; const float* h3b1 = (const float*)d_in[29];
  const float* h3w2 = (const float*)d_in[30]; const float* h3b2 = (const float*)d_in[31];
  const float* h3w3 = (const float*)d_in[32]; const float* h3b3 = (const float*)d_in[33];
  float* out = (float*)d_out;
  const dim3 blk(256);

  // ---- fast-path workspace carve (224 MiB) ----
  char* p = (char*)d_ws;
  float* h    = (float*)p;          p += (size_t)MTOK*DD*4;          // residual
  float* hn   = (float*)p;          p += (size_t)MTOK*DD*4;          // attn out (f32)
  float* qkv  = (float*)p;          p += (size_t)MTOK*3*DD*4;        // qkv f32
  float* uvc  = (float*)p;          p += (size_t)MCHUNK*2*FF*4;      // uv chunk / t2
  unsigned short* Wthi  = (unsigned short*)p; p += (size_t)DD*2*FF*2;   // max weight: w1
  unsigned short* Wtlo  = (unsigned short*)p; p += (size_t)DD*2*FF*2;
  unsigned short* Wt2hi = (unsigned short*)p; p += (size_t)FF*DD*2;     // w2
  unsigned short* Wt2lo = (unsigned short*)p; p += (size_t)FF*DD*2;
  unsigned short* Ahi   = (unsigned short*)p; p += (size_t)MTOK*3*DD*2; // A operand (max: cat)
  unsigned short* Alo   = (unsigned short*)p; p += (size_t)MTOK*3*DD*2;
  unsigned short* A2hi  = (unsigned short*)p; p += (size_t)MTOK*DD*2;   // geglu-out chunk / t1
  unsigned short* A2lo  = (unsigned short*)p; p += (size_t)MTOK*DD*2;
  const size_t need_fast = (size_t)(p - (char*)d_ws);

  if (ws_size >= need_fast) {
    // =========================== MFMA fast path ===========================
    for (int l = 0; l < LL; ++l) {
      const float* xin = (l == 0) ? acc_fea : h;
      // hn1 = LN(x, g1) -> Ahi/Alo directly
      ln_hilo_kernel<<<MTOK, blk, 0, stream>>>(xin, DD, ln1 + (size_t)l*DD, Ahi, Alo, DD);
      // qkv = hn1 @ Wqkv + bqkv
      transpose_hilo<<<dim3(3*DD/32, DD/32), blk, 0, stream>>>(
          wqkv + (size_t)l*DD*3*DD, DD, 3*DD, Wthi, Wtlo);
      gemm_mfma<<<dim3(3*DD/128, MTOK/128), blk, 0, stream>>>(
          Ahi, Alo, DD, Wthi, Wtlo, 3*DD, DD,
          bqkv + (size_t)l*3*DD, nullptr, 0, qkv, 3*DD, nullptr, nullptr, 0);
      // attn -> hn
      attn_kernel<<<dim3(SS/64, HH, BB), blk, 0, stream>>>(qkv, hn);
      // h = xin + attn_o @ Wo + bo
      conv_hilo<<<dim3(2048), blk, 0, stream>>>(hn, Ahi, Alo, MTOK*DD/4);
      transpose_hilo<<<dim3(DD/32, DD/32), blk, 0, stream>>>(
          wo + (size_t)l*DD*DD, DD, DD, Wthi, Wtlo);
      gemm_mfma<<<dim3(DD/128, MTOK/128), blk, 0, stream>>>(
          Ahi, Alo, DD, Wthi, Wtlo, DD, DD,
          bo + (size_t)l*DD, xin, DD, h, DD, nullptr, nullptr, 0);
      // hn2 = LN(h, g2) -> Ahi/Alo
      ln_hilo_kernel<<<MTOK, blk, 0, stream>>>(h, DD, ln2 + (size_t)l*DD, Ahi, Alo, DD);
      // MLP (chunked): uv = hn2 @ W1 + b1; gg = geglu(uv); h += gg @ W2 + b2
      transpose_hilo<<<dim3(2*FF/32, DD/32), blk, 0, stream>>>(
          w1 + (size_t)l*DD*2*FF, DD, 2*FF, Wthi, Wtlo);
      transpose_hilo<<<dim3(DD/32, FF/32), blk, 0, stream>>>(
          w2 + (size_t)l*FF*DD, FF, DD, Wt2hi, Wt2lo);
      for (int c = 0; c < MTOK/MCHUNK; ++c) {
        const size_t ro = (size_t)c * MCHUNK;
        gemm_mfma<<<dim3(2*FF/128, MCHUNK/128), blk, 0, stream>>>(
            Ahi + ro*DD, Alo + ro*DD, DD, Wthi, Wtlo, 2*FF, DD,
            b1 + (size_t)l*2*FF, nullptr, 0, uvc, 2*FF, nullptr, nullptr, 0);
        geglu_hilo<<<(MCHUNK*(FF/4))/256, blk, 0, stream>>>(uvc, A2hi, A2lo);
        gemm_mfma<<<dim3(DD/128, MCHUNK/128), blk, 0, stream>>>(
            A2hi, A2lo, FF, Wt2hi, Wt2lo, DD, FF,
            b2 + (size_t)l*DD, h + ro*DD, DD, h + ro*DD, DD, nullptr, nullptr, 0);
      }
    }
    // cat3 (bf16 hi/lo, ld 3072) = [ LN(h,lnf) | emb1[c1] | emb2[c2] ]
    ln_hilo_kernel<<<MTOK, blk, 0, stream>>>(h, DD, lnf, Ahi, Alo, 3*DD);
    gather_hilo<<<MTOK, blk, 0, stream>>>(c1, c2, emb1, emb2, Ahi, Alo);

    const float* hw1[3] = {h1w1, h2w1, h3w1};
    const float* hb1[3] = {h1b1, h2b1, h3b1};
    const float* hw2[3] = {h1w2, h2w2, h3w2};
    const float* hb2[3] = {h1b2, h2b2, h3b2};
    const float* hw3[3] = {h1w3, h2w3, h3w3};
    const float* hb3[3] = {h1b3, h2b3, h3b3};
    const int   hk [3] = {DD, 2*DD, 3*DD};
    const int   hn3[3] = {QN+2, QN, QN};
    const int   hoff[3] = {0, QN+2, QN+2+QN};
    float* t2 = uvc;
    for (int hd = 0; hd < 3; ++hd) {
      const int K1 = hk[hd];
      // t1 = relu(cat[:, :K1] @ w1 + b1) -> A2 (bf16 hi/lo)
      transpose_hilo<<<dim3(DD/32, K1/32), blk, 0, stream>>>(hw1[hd], K1, DD, Wthi, Wtlo);
      gemm_mfma<<<dim3(DD/128, MTOK/128), blk, 0, stream>>>(
          Ahi, Alo, 3*DD, Wthi, Wtlo, DD, K1,
          hb1[hd], nullptr, 0, nullptr, DD, A2hi, A2lo, 2);
      // t2 = relu(t1 @ w2 + b2) -> f32
      transpose_hilo<<<dim3(DD/32, DD/32), blk, 0, stream>>>(hw2[hd], DD, DD, Wthi, Wtlo);
      gemm_mfma<<<dim3(DD/128, MTOK/128), blk, 0, stream>>>(
          A2hi, A2lo, DD, Wthi, Wtlo, DD, DD,
          hb2[hd], nullptr, 0, t2, DD, nullptr, nullptr, 1);
      // out slice = t2 @ w3 + b3 (tiny N: fp32 SIMT)
      gemm_f32<<<dim3((hn3[hd]+127)/128, MTOK/128), blk, 0, stream>>>(
          t2, DD, hw3[hd], hn3[hd], hn3[hd], DD, hb3[hd], nullptr, 0,
          out + hoff[hd], 386, 0);
    }
    return;
  }

  // ---- fp32 fallback carve (128 MiB) ----
  float* fh   = (float*)d_ws;
  float* fhn  = fh   + (size_t)MTOK*DD;
  float* fqkv = fhn  + (size_t)MTOK*DD;
  float* fuvc = fqkv + (size_t)MTOK*3*DD;
  float* fggc = fuvc + (size_t)MCHUNK*2*FF;
  const size_t need_f32 =
      ((size_t)MTOK*DD*2 + (size_t)MTOK*3*DD + (size_t)MCHUNK*2*FF + (size_t)MCHUNK*FF)
      * sizeof(float);
  if (ws_size < need_f32) {
    hipMemsetAsync(d_out, 0, (size_t)out_size * sizeof(float), stream);
    return;
  }

  const dim3 g_m(DD/128, MTOK/128);
  for (int l = 0; l < LL; ++l) {
    const float* xin = (l == 0) ? acc_fea : fh;
    ln_kernel<<<MTOK, blk, 0, stream>>>(xin, DD, ln1 + (size_t)l*DD, fhn, DD);
    gemm_f32<<<dim3(3*DD/128, MTOK/128), blk, 0, stream>>>(
        fhn, DD, wqkv + (size_t)l*DD*3*DD, 3*DD, 3*DD, DD,
        bqkv + (size_t)l*3*DD, nullptr, 0, fqkv, 3*DD, 0);
    attn_kernel<<<dim3(SS/64, HH, BB), blk, 0, stream>>>(fqkv, fhn);
    gemm_f32<<<g_m, blk, 0, stream>>>(
        fhn, DD, wo + (size_t)l*DD*DD, DD, DD, DD,
        bo + (size_t)l*DD, xin, DD, fh, DD, 0);
    ln_kernel<<<MTOK, blk, 0, stream>>>(fh, DD, ln2 + (size_t)l*DD, fhn, DD);
    for (int c = 0; c < MTOK/MCHUNK; ++c) {
      const size_t ro = (size_t)c * MCHUNK;
      gemm_f32<<<dim3(2*FF/128, MCHUNK/128), blk, 0, stream>>>(
          fhn + ro*DD, DD, w1 + (size_t)l*DD*2*FF, 2*FF, 2*FF, DD,
          b1 + (size_t)l*2*FF, nullptr, 0, fuvc, 2*FF, 0);
      geglu_kernel<<<(MCHUNK*(FF/4))/256, blk, 0, stream>>>(fuvc, fggc);
      gemm_f32<<<dim3(DD/128, MCHUNK/128), blk, 0, stream>>>(
          fggc, FF, w2 + (size_t)l*FF*DD, DD, DD, FF,
          b2 + (size_t)l*DD, fh + ro*DD, DD, fh + ro*DD, DD, 0);
    }
  }
  float* cat = fqkv;
  ln_kernel<<<MTOK, blk, 0, stream>>>(fh, DD, lnf, cat, 3*DD);
  gather_kernel<<<MTOK, blk, 0, stream>>>(c1, c2, emb1, emb2, cat);
  float* t1 = fuvc;
  float* t2 = fuvc + (size_t)MTOK*DD;
  gemm_f32<<<g_m, blk, 0, stream>>>(cat, 3*DD, h1w1, DD, DD, DD,   h1b1, nullptr, 0, t1, DD, 1);
  gemm_f32<<<g_m, blk, 0, stream>>>(t1,  DD,   h1w2, DD, DD, DD,   h1b2, nullptr, 0, t2, DD, 1);
  gemm_f32<<<dim3(2, MTOK/128), blk, 0, stream>>>(
      t2, DD, h1w3, QN+2, QN+2, DD, h1b3, nullptr, 0, out, 386, 0);
  gemm_f32<<<g_m, blk, 0, stream>>>(cat, 3*DD, h2w1, DD, DD, 2*DD, h2b1, nullptr, 0, t1, DD, 1);
  gemm_f32<<<g_m, blk, 0, stream>>>(t1,  DD,   h2w2, DD, DD, DD,   h2b2, nullptr, 0, t2, DD, 1);
  gemm_f32<<<dim3(1, MTOK/128), blk, 0, stream>>>(
      t2, DD, h2w3, QN, QN, DD, h2b3, nullptr, 0, out + 130, 386, 0);
  gemm_f32<<<g_m, blk, 0, stream>>>(cat, 3*DD, h3w1, DD, DD, 3*DD, h3b1, nullptr, 0, t1, DD, 1);
  gemm_f32<<<g_m, blk, 0, stream>>>(t1,  DD,   h3w2, DD, DD, DD,   h3b2, nullptr, 0, t2, DD, 1);
  gemm_f32<<<dim3(1, MTOK/128), blk, 0, stream>>>(
      t2, DD, h3w3, QN, QN, DD, h3b3, nullptr, 0, out + 258, 386, 0);
}